// Round 7
// baseline (1620.360 us; speedup 1.0000x reference)
//
#include <hip/hip_runtime.h>
#include <hip/hip_bf16.h>
#include <hip/hip_fp16.h>

typedef unsigned int u32;
typedef unsigned short u16;
typedef short s16x8 __attribute__((ext_vector_type(8)));
typedef float f32x4 __attribute__((ext_vector_type(4)));

#define T_STEPS 256

// ---------------- helpers ----------------
__device__ __forceinline__ u16 f2bu(float f) {
  return __bfloat16_as_ushort(__float2bfloat16(f));
}
__device__ __forceinline__ float fast_tanh(float x) {
  float ax = fabsf(x);
  float e = __expf(-2.f * ax);
  float r = 1.f - 2.f * e / (1.f + e);
  return copysignf(r, x);
}
__device__ __forceinline__ __half2 bch2(u32 v) {
  return __builtin_bit_cast(__half2, v);
}
__device__ __forceinline__ void gload_lds16(const void* g, void* l) {
  __builtin_amdgcn_global_load_lds((const __attribute__((address_space(1))) u32*)g,
                                   (__attribute__((address_space(3))) u32*)l, 16, 0, 0);
}
// add value from DPP-permuted lane (VALU pipe, no LDS); CTRL must be constant
template <int CTRL>
__device__ __forceinline__ float dppadd(float x) {
  int r = __builtin_amdgcn_update_dpp(0, __builtin_bit_cast(int, x), CTRL, 0xf, 0xf, true);
  return x + __builtin_bit_cast(float, r);
}

// ---------------- x f32 -> bf16 ----------------
__global__ void k_cvt_bf16(const float* __restrict__ in, u16* __restrict__ out, int n4) {
  int i = blockIdx.x * blockDim.x + threadIdx.x;
  if (i >= n4) return;
  const float4 v = ((const float4*)in)[i];
  ushort4 o;
  o.x = f2bu(v.x); o.y = f2bu(v.y); o.z = f2bu(v.z); o.w = f2bu(v.w);
  ((ushort4*)out)[i] = o;
}

// ---------------- weight prep (per layer) ----------------
// BcatT [1024][512] bf16: x-proj weights (h|o concat), transposed
// WhoT  [512][512]  bf16: h-part of Wo, transposed
// Wpack 131072 u32 for k_scan3: thread j (ks=j&7, c=j>>3), pass p (C=p*64+c),
//   pair i (k=ks*64+2i):
//   REG  i in [0,16):  word (p*16+i)*512 + j
//   LDS  i in [16,20): word 65536 + (p*512+j)*4 + (i-16)
//   STR  i in [20,32): word 81920 + ((p*3+g)*512+j)*4 + q, i = 20+g*4+q
__global__ void k_prep_w(const float* __restrict__ Wh, const float* __restrict__ Wo,
                         u16* __restrict__ BcatT, u16* __restrict__ WhoT,
                         u32* __restrict__ Wpack) {
  int idx = blockIdx.x * 256 + threadIdx.x;
  if (idx < 1024 * 512) {
    int n = idx >> 9, k = idx & 511;
    float v = (n < 512) ? Wh[k * 512 + n] : Wo[k * 512 + (n - 512)];
    BcatT[idx] = f2bu(v);
  } else if (idx < 1024 * 512 + 512 * 512) {
    int t = idx - 1024 * 512;
    int n = t >> 9, k = t & 511;
    WhoT[t] = f2bu(Wo[(512 + k) * 512 + n]);
  } else {
    int w2 = idx - (1024 * 512 + 512 * 512);
    int p, i, j;
    if (w2 < 65536) {
      p = w2 >> 13; i = (w2 >> 9) & 15; j = w2 & 511;
    } else if (w2 < 81920) {
      int t = w2 - 65536;
      p = t >> 11; j = (t >> 2) & 511; i = 16 + (t & 3);
    } else {
      int t = w2 - 81920;
      int row = t >> 11;            // p*3+g
      p = row / 3; int g = row - 3 * p;
      j = (t >> 2) & 511; i = 20 + g * 4 + (t & 3);
    }
    int ks = j & 7, c = j >> 3;
    int C = p * 64 + c;
    int k = ks * 64 + 2 * i;
    u16 a = __half_as_ushort(__float2half(Wh[(512 + k) * 512 + C]));
    u16 b = __half_as_ushort(__float2half(Wh[(512 + k + 1) * 512 + C]));
    Wpack[w2] = (u32)a | ((u32)b << 16);
  }
}

// ---------------- bf16 MFMA GEMM: C[M x N] = A[M x 512] * BT[N x 512]^T ----------------
template <int MODE>
__global__ __launch_bounds__(256) void k_gemm(
    const u16* __restrict__ A, const u16* __restrict__ BT, int NX,
    __half* __restrict__ outH, u16* __restrict__ outB, float* __restrict__ outF,
    const __half* __restrict__ Uo, const float* __restrict__ biasH,
    const float* __restrict__ biasO) {
  __shared__ __align__(16) u16 As[128 * 64], Bs[128 * 64];
  const int bid = blockIdx.x;
  const int bn = bid % NX, bm = bid / NX;
  const int m0 = bm * 128, n0 = bn * 128;
  const int tid = threadIdx.x, w = tid >> 6, l = tid & 63;
  const int l15 = l & 15, lk = (l >> 4) << 3;
  f32x4 acc[4][4] = {};
  for (int kt = 0; kt < 8; ++kt) {
    const int k0 = kt * 64;
#pragma unroll
    for (int i = 0; i < 4; ++i) {
      int idx = w * 4 + i;
      int ob = idx * 1024 + l * 16;
      int row = ob >> 7, cb = ob & 127;
      int scb = cb ^ ((row & 7) << 4);
      gload_lds16((const char*)A + (size_t)(m0 + row) * 1024 + k0 * 2 + scb,
                  (char*)As + idx * 1024);
      gload_lds16((const char*)BT + (size_t)(n0 + row) * 1024 + k0 * 2 + scb,
                  (char*)Bs + idx * 1024);
    }
    __syncthreads();
    const int wr = (w >> 1) * 64, wc = (w & 1) * 64;
#pragma unroll
    for (int kk = 0; kk < 2; ++kk) {
      s16x8 af[4], bfr[4];
      const int kb = (kk * 32 + lk) * 2;
#pragma unroll
      for (int i = 0; i < 4; ++i) {
        int ar = wr + i * 16 + l15;
        af[i] = *(const s16x8*)((const char*)As + ar * 128 + (kb ^ ((ar & 7) << 4)));
        int br = wc + i * 16 + l15;
        bfr[i] = *(const s16x8*)((const char*)Bs + br * 128 + (kb ^ ((br & 7) << 4)));
      }
#pragma unroll
      for (int i = 0; i < 4; ++i)
#pragma unroll
        for (int jj = 0; jj < 4; ++jj)
          acc[i][jj] = __builtin_amdgcn_mfma_f32_16x16x32_bf16(af[i], bfr[jj], acc[i][jj], 0, 0, 0);
    }
    __syncthreads();
  }
#pragma unroll
  for (int i = 0; i < 4; ++i)
#pragma unroll
    for (int jj = 0; jj < 4; ++jj)
#pragma unroll
      for (int rr = 0; rr < 4; ++rr) {
        int row = m0 + (w >> 1) * 64 + i * 16 + ((l >> 4) << 2) + rr;
        int col = n0 + (w & 1) * 64 + jj * 16 + l15;
        float v = acc[i][jj][rr];
        if (MODE == 0) {
          float bsv = (col < 512) ? biasH[col] : biasO[col - 512];
          outH[(size_t)row * 1024 + col] = __float2half(v + bsv);
        } else {
          float o = fast_tanh(v + __half2float(Uo[(size_t)row * 1024 + col]));
          if (MODE == 1) outB[(size_t)row * 512 + col] = f2bu(o);
          else           outF[(size_t)row * 512 + col] = o;
        }
      }
}

// ---------------- recurrent scan v3: 8-way k-split ----------------
// Thread j: ks=j&7 (k-slice of 64), c=j>>3. 8 passes, pass p -> column C=p*64+c.
// h slice (64 f16) in regs, refreshed once/step (8 b128, conflict-free via
// 144B slice stride). Reduce over the 8-lane group via 3 DPP adds (VALU pipe).
// W: 128 pairs VGPR + 32 pairs LDS (64KB) + 96 pairs streamed from L2
// (double-buffered one pass ahead). One barrier/step.
#define HB_SLICE 144
#define HB_PAR (8 * HB_SLICE)                 // 1152 B per parity
#define SCAN3_LDS_BYTES (65536 + 2 * HB_PAR)  // 67840

__global__ __launch_bounds__(512) __attribute__((amdgpu_waves_per_eu(2, 2)))
void k_scan3(const u32* __restrict__ Wpk, const __half* __restrict__ Uh,
             const float* __restrict__ h0, u16* __restrict__ Hseq) {
  extern __shared__ __align__(16) u32 smem[];
  u32* Wl = smem;                      // [8 p][512 j][4] u32, byte (p*512+j)*16
  char* hb = (char*)(smem + 16384);    // 2 parities x 1152B
  const int b = blockIdx.x, j = threadIdx.x;
  const int ks = j & 7, c = j >> 3;
  const size_t r0 = (size_t)b * T_STEPS;

  u32 wreg[128];
#pragma unroll
  for (int p8 = 0; p8 < 128; ++p8) wreg[p8] = Wpk[p8 * 512 + j];
  {
    const u32* src = Wpk + 65536;
#pragma unroll
    for (int p = 0; p < 8; ++p)
      gload_lds16(src + (p * 512 + j) * 4, (char*)Wl + (p * 512 + (j & ~63)) * 16);
  }
  {
    float hv = h0 ? h0[b * 512 + j] : 0.f;
    *(__half*)(hb + (j >> 6) * HB_SLICE + (j & 63) * 2) = __float2half(hv);
    Hseq[r0 * 512 + j] = f2bu(hv);
  }
  const u32* Wst = Wpk + 81920;
  u32 sbufA[12], sbufB[12];
#pragma unroll
  for (int g = 0; g < 3; ++g) {
    uint4 v = *(const uint4*)(Wst + ((0 * 3 + g) * 512 + j) * 4);
    sbufA[g * 4 + 0] = v.x; sbufA[g * 4 + 1] = v.y;
    sbufA[g * 4 + 2] = v.z; sbufA[g * 4 + 3] = v.w;
  }
  float u_pre[8];
#pragma unroll
  for (int p = 0; p < 8; ++p) u_pre[p] = __half2float(Uh[r0 * 1024 + p * 64 + c]);
  __syncthreads();   // drains gload_lds + makes h visible

  int par = 0;
  for (int t = 0; t < T_STEPS; ++t) {
    // h slice -> regs (8 x b128, 8 distinct addrs, conflict-free)
    u32 hsv[32];
    {
      const char* hbp = hb + par * HB_PAR + ks * HB_SLICE;
#pragma unroll
      for (int i = 0; i < 8; ++i) {
        uint4 v = *(const uint4*)(hbp + i * 16);
        hsv[i * 4 + 0] = v.x; hsv[i * 4 + 1] = v.y;
        hsv[i * 4 + 2] = v.z; hsv[i * 4 + 3] = v.w;
      }
    }
    float u_cur[8];
#pragma unroll
    for (int p = 0; p < 8; ++p) u_cur[p] = u_pre[p];
    if (t + 1 < T_STEPS) {
#pragma unroll
      for (int p = 0; p < 8; ++p)
        u_pre[p] = __half2float(Uh[(r0 + t + 1) * 1024 + p * 64 + c]);
    }
#pragma unroll
    for (int p = 0; p < 8; ++p) {
      u32* scur = (p & 1) ? sbufB : sbufA;
      u32* snxt = (p & 1) ? sbufA : sbufB;
      // prefetch stream pairs for pass (p+1)&7 (next step's p=0 at p==7)
#pragma unroll
      for (int g = 0; g < 3; ++g) {
        uint4 v = *(const uint4*)(Wst + ((((p + 1) & 7) * 3 + g) * 512 + j) * 4);
        snxt[g * 4 + 0] = v.x; snxt[g * 4 + 1] = v.y;
        snxt[g * 4 + 2] = v.z; snxt[g * 4 + 3] = v.w;
      }
      uint4 wlv = *(const uint4*)((const char*)Wl + (p * 512 + j) * 16);
      u32 wlw[4] = {wlv.x, wlv.y, wlv.z, wlv.w};
      __half2 a0 = __float2half2_rn(0.f), a1 = a0;
#pragma unroll
      for (int i = 0; i < 16; ++i) {
        __half2& a = (i & 1) ? a1 : a0;
        a = __hfma2(bch2(wreg[p * 16 + i]), bch2(hsv[i]), a);
      }
#pragma unroll
      for (int i = 0; i < 4; ++i) {
        __half2& a = (i & 1) ? a1 : a0;
        a = __hfma2(bch2(wlw[i]), bch2(hsv[16 + i]), a);
      }
#pragma unroll
      for (int i = 0; i < 12; ++i) {
        __half2& a = (i & 1) ? a1 : a0;
        a = __hfma2(bch2(scur[i]), bch2(hsv[20 + i]), a);
      }
      float sm = __low2float(a0) + __high2float(a0) +
                 __low2float(a1) + __high2float(a1);
      sm = dppadd<0xB1>(sm);    // quad_perm xor1
      sm = dppadd<0x4E>(sm);    // quad_perm xor2
      sm = dppadd<0x141>(sm);   // row_half_mirror: cross-quad within 8
      float f = fast_tanh(sm + u_cur[p]);
      if (ks == 0)
        *(__half*)(hb + (par ^ 1) * HB_PAR + p * HB_SLICE + c * 2) = __float2half(f);
      if (ks == 1 && t + 1 < T_STEPS)
        Hseq[(r0 + t + 1) * 512 + p * 64 + c] = f2bu(f);
    }
    __syncthreads();
    par ^= 1;
  }
}

// ---------------- launch ----------------
extern "C" void kernel_launch(void* const* d_in, const int* in_sizes, int n_in,
                              void* d_out, int out_size, void* d_ws, size_t ws_size,
                              hipStream_t stream) {
  const float* x   = (const float*)d_in[0];
  const float* enc = (const float*)d_in[1];
  const float* Wh0 = (const float*)d_in[2];
  const float* bh0 = (const float*)d_in[3];
  const float* Wo0 = (const float*)d_in[4];
  const float* bo0 = (const float*)d_in[5];
  const float* Wh1 = (const float*)d_in[6];
  const float* bh1 = (const float*)d_in[7];
  const float* Wo1 = (const float*)d_in[8];
  const float* bo1 = (const float*)d_in[9];
  char* ws = (char*)d_ws;
  u16*    Xbf   = (u16*)(ws);
  __half* U     = (__half*)(ws + 16777216);
  u16*    Hs0   = (u16*)(ws + 16777216 + 33554432);
  u16*    Out0  = (u16*)(ws + 16777216 + 33554432 + 16777216);
  u16*    Hs1   = (u16*)(ws + 16777216 + 33554432 + 2 * 16777216);
  char*   wb    = ws + 16777216 + 33554432 + 3 * 16777216;
  u16*    Bct0  = (u16*)(wb);
  u16*    WhoT0 = (u16*)(wb + 1048576);
  u32*    Wpk0  = (u32*)(wb + 1048576 + 524288);
  u16*    Bct1  = (u16*)(wb + 1048576 + 2 * 524288);
  u16*    WhoT1 = (u16*)(wb + 2 * 1048576 + 2 * 524288);
  u32*    Wpk1  = (u32*)(wb + 2 * 1048576 + 3 * 524288);

  (void)hipFuncSetAttribute((const void*)k_scan3,
                            hipFuncAttributeMaxDynamicSharedMemorySize,
                            SCAN3_LDS_BYTES);

  k_cvt_bf16<<<8192, 256, 0, stream>>>(x, Xbf, 8388608 / 4);
  k_prep_w<<<3584, 256, 0, stream>>>(Wh0, Wo0, Bct0, WhoT0, Wpk0);
  k_prep_w<<<3584, 256, 0, stream>>>(Wh1, Wo1, Bct1, WhoT1, Wpk1);
  k_gemm<0><<<1024, 256, 0, stream>>>(Xbf, Bct0, 8, U, nullptr, nullptr, nullptr, bh0, bo0);
  k_scan3<<<64, 512, SCAN3_LDS_BYTES, stream>>>(Wpk0, U, enc, Hs0);
  k_gemm<1><<<512, 256, 0, stream>>>(Hs0, WhoT0, 4, nullptr, Out0, nullptr, U + 512, nullptr, nullptr);
  k_gemm<0><<<1024, 256, 0, stream>>>(Out0, Bct1, 8, U, nullptr, nullptr, nullptr, bh1, bo1);
  k_scan3<<<64, 512, SCAN3_LDS_BYTES, stream>>>(Wpk1, U, nullptr, Hs1);
  k_gemm<2><<<512, 256, 0, stream>>>(Hs1, WhoT1, 4, nullptr, nullptr, (float*)d_out, U + 512, nullptr, nullptr);
}

// Round 8
// 1216.726 us; speedup vs baseline: 1.3317x; 1.3317x over previous
//
#include <hip/hip_runtime.h>
#include <hip/hip_bf16.h>
#include <hip/hip_fp16.h>

typedef unsigned int u32;
typedef unsigned short u16;
typedef short s16x8 __attribute__((ext_vector_type(8)));
typedef float f32x4 __attribute__((ext_vector_type(4)));

#define T_STEPS 256

// ---------------- helpers ----------------
__device__ __forceinline__ u16 f2bu(float f) {
  return __bfloat16_as_ushort(__float2bfloat16(f));
}
__device__ __forceinline__ float fast_tanh(float x) {
  float ax = fabsf(x);
  float e = __expf(-2.f * ax);
  float r = 1.f - 2.f * e / (1.f + e);
  return copysignf(r, x);
}
__device__ __forceinline__ __half2 bch2(u32 v) {
  return __builtin_bit_cast(__half2, v);
}
__device__ __forceinline__ void gload_lds16(const void* g, void* l) {
  __builtin_amdgcn_global_load_lds((const __attribute__((address_space(1))) u32*)g,
                                   (__attribute__((address_space(3))) u32*)l, 16, 0, 0);
}
// add value from DPP-permuted lane (VALU pipe, no LDS); CTRL constant
template <int CTRL>
__device__ __forceinline__ float dppadd(float x) {
  int r = __builtin_amdgcn_update_dpp(0, __builtin_bit_cast(int, x), CTRL, 0xf, 0xf, true);
  return x + __builtin_bit_cast(float, r);
}

// ---------------- x f32 -> bf16 ----------------
__global__ void k_cvt_bf16(const float* __restrict__ in, u16* __restrict__ out, int n4) {
  int i = blockIdx.x * blockDim.x + threadIdx.x;
  if (i >= n4) return;
  const float4 v = ((const float4*)in)[i];
  ushort4 o;
  o.x = f2bu(v.x); o.y = f2bu(v.y); o.z = f2bu(v.z); o.w = f2bu(v.w);
  ((ushort4*)out)[i] = o;
}

// ---------------- weight prep (per layer) ----------------
// BcatT [1024][512] bf16: x-proj weights (h|o concat), transposed
// WhoT  [512][512]  bf16: h-part of Wo, transposed
// Wpack 131072 u32 for k_scan4. Thread j: ks=j&3, c0=j>>2; col p: C=p*128+c0;
// pair i in [0,64): k = ks*128 + 2i.
//  REG  i in [0,48):  word (( (i>>2)*16 + p*4 + (i&3) ))*512 + j
//  LDS  i in [48,64): word 98304 + (((p*4 + ((i-48)>>2))*512 + j)*4) + ((i-48)&3)
__global__ void k_prep_w(const float* __restrict__ Wh, const float* __restrict__ Wo,
                         u16* __restrict__ BcatT, u16* __restrict__ WhoT,
                         u32* __restrict__ Wpack) {
  int idx = blockIdx.x * 256 + threadIdx.x;
  if (idx < 1024 * 512) {
    int n = idx >> 9, k = idx & 511;
    float v = (n < 512) ? Wh[k * 512 + n] : Wo[k * 512 + (n - 512)];
    BcatT[idx] = f2bu(v);
  } else if (idx < 1024 * 512 + 512 * 512) {
    int t = idx - 1024 * 512;
    int n = t >> 9, k = t & 511;
    WhoT[t] = f2bu(Wo[(512 + k) * 512 + n]);
  } else {
    int w2 = idx - (1024 * 512 + 512 * 512);
    int i, j, col;
    if (w2 < 98304) {
      int p = w2 >> 9; j = w2 & 511;
      int g = p >> 4, r = p & 15;
      col = r >> 2; int q = r & 3;
      i = 4 * g + q;                 // [0,48)
    } else {
      int t = w2 - 98304;
      int q = t & 3; j = (t >> 2) & 511;
      int grp = t >> 11;             // [0,16)
      col = grp >> 2; int g2 = grp & 3;
      i = 48 + g2 * 4 + q;           // [48,64)
    }
    int ks = j & 3, c0 = j >> 2;
    int C = col * 128 + c0;
    int k = ks * 128 + 2 * i;
    u16 a = __half_as_ushort(__float2half(Wh[(512 + k) * 512 + C]));
    u16 b = __half_as_ushort(__float2half(Wh[(512 + k + 1) * 512 + C]));
    Wpack[w2] = (u32)a | ((u32)b << 16);
  }
}

// ---------------- bf16 MFMA GEMM: C[M x N] = A[M x 512] * BT[N x 512]^T ----------------
template <int MODE>
__global__ __launch_bounds__(256) void k_gemm(
    const u16* __restrict__ A, const u16* __restrict__ BT, int NX,
    __half* __restrict__ outH, u16* __restrict__ outB, float* __restrict__ outF,
    const __half* __restrict__ Uo, const float* __restrict__ biasH,
    const float* __restrict__ biasO) {
  __shared__ __align__(16) u16 As[128 * 64], Bs[128 * 64];
  const int bid = blockIdx.x;
  const int bn = bid % NX, bm = bid / NX;
  const int m0 = bm * 128, n0 = bn * 128;
  const int tid = threadIdx.x, w = tid >> 6, l = tid & 63;
  const int l15 = l & 15, lk = (l >> 4) << 3;
  f32x4 acc[4][4] = {};
  for (int kt = 0; kt < 8; ++kt) {
    const int k0 = kt * 64;
#pragma unroll
    for (int i = 0; i < 4; ++i) {
      int idx = w * 4 + i;
      int ob = idx * 1024 + l * 16;
      int row = ob >> 7, cb = ob & 127;
      int scb = cb ^ ((row & 7) << 4);
      gload_lds16((const char*)A + (size_t)(m0 + row) * 1024 + k0 * 2 + scb,
                  (char*)As + idx * 1024);
      gload_lds16((const char*)BT + (size_t)(n0 + row) * 1024 + k0 * 2 + scb,
                  (char*)Bs + idx * 1024);
    }
    __syncthreads();
    const int wr = (w >> 1) * 64, wc = (w & 1) * 64;
#pragma unroll
    for (int kk = 0; kk < 2; ++kk) {
      s16x8 af[4], bfr[4];
      const int kb = (kk * 32 + lk) * 2;
#pragma unroll
      for (int i = 0; i < 4; ++i) {
        int ar = wr + i * 16 + l15;
        af[i] = *(const s16x8*)((const char*)As + ar * 128 + (kb ^ ((ar & 7) << 4)));
        int br = wc + i * 16 + l15;
        bfr[i] = *(const s16x8*)((const char*)Bs + br * 128 + (kb ^ ((br & 7) << 4)));
      }
#pragma unroll
      for (int i = 0; i < 4; ++i)
#pragma unroll
        for (int jj = 0; jj < 4; ++jj)
          acc[i][jj] = __builtin_amdgcn_mfma_f32_16x16x32_bf16(af[i], bfr[jj], acc[i][jj], 0, 0, 0);
    }
    __syncthreads();
  }
#pragma unroll
  for (int i = 0; i < 4; ++i)
#pragma unroll
    for (int jj = 0; jj < 4; ++jj)
#pragma unroll
      for (int rr = 0; rr < 4; ++rr) {
        int row = m0 + (w >> 1) * 64 + i * 16 + ((l >> 4) << 2) + rr;
        int col = n0 + (w & 1) * 64 + jj * 16 + l15;
        float v = acc[i][jj][rr];
        if (MODE == 0) {
          float bsv = (col < 512) ? biasH[col] : biasO[col - 512];
          outH[(size_t)row * 1024 + col] = __float2half(v + bsv);
        } else {
          float o = fast_tanh(v + __half2float(Uo[(size_t)row * 1024 + col]));
          if (MODE == 1) outB[(size_t)row * 512 + col] = f2bu(o);
          else           outF[(size_t)row * 512 + col] = o;
        }
      }
}

// ---------------- recurrent scan v4: 4-col x 4-way-k blocking ----------------
// Thread j: ks=j&3 (k-quarter), c0=j>>2. Owns cols {c0,c0+128,c0+256,c0+384},
// k in [ks*128, ks*128+128) -> 64 pairs/col, 256 total: 192 reg/AGPR + 64 LDS
// (128KB, [16 grp][512 j] uint4). h-chunk loaded once, reused for 4 cols:
// 16 h b128 + 16 W b128 per thread/step (vs 80 in R3). Cross-k reduce = 2 DPP
// quad-perm adds. 1 barrier/step, double-buffered h, u prefetched 1 ahead.
#define SCAN4_LDS_BYTES (131072 + 2048)

__global__ __launch_bounds__(512, 2)
void k_scan4(const u32* __restrict__ Wpk, const __half* __restrict__ Uh,
             const float* __restrict__ h0, u16* __restrict__ Hseq) {
  extern __shared__ __align__(16) u32 smem[];
  uint4* Wl4 = (uint4*)smem;                 // [16 grp][512 j]
  char* hb = (char*)smem + 131072;           // 2 parities x 1024B
  const int b = blockIdx.x, j = threadIdx.x;
  const int ks = j & 3, c0 = j >> 2;
  const size_t r0 = (size_t)b * T_STEPS;
  u32 wreg[192];
#pragma unroll
  for (int p = 0; p < 192; ++p) wreg[p] = Wpk[p * 512 + j];
#pragma unroll
  for (int g = 0; g < 16; ++g)
    Wl4[g * 512 + j] = *(const uint4*)(Wpk + 98304 + ((size_t)g * 512 + j) * 4);
  {
    float hv = h0 ? h0[b * 512 + j] : 0.f;
    *(__half*)(hb + j * 2) = __float2half(hv);
    Hseq[r0 * 512 + j] = f2bu(hv);
  }
  float u0 = __half2float(Uh[r0 * 1024 + c0]);
  float u1 = __half2float(Uh[r0 * 1024 + 128 + c0]);
  float u2 = __half2float(Uh[r0 * 1024 + 256 + c0]);
  float u3 = __half2float(Uh[r0 * 1024 + 384 + c0]);
  __syncthreads();
  int par = 0;
  for (int t = 0; t < T_STEPS; ++t) {
    float un0 = 0.f, un1 = 0.f, un2 = 0.f, un3 = 0.f;
    if (t + 1 < T_STEPS) {
      const __half* up = Uh + (r0 + t + 1) * 1024;
      un0 = __half2float(up[c0]);       un1 = __half2float(up[128 + c0]);
      un2 = __half2float(up[256 + c0]); un3 = __half2float(up[384 + c0]);
    }
    const uint4* h4 = (const uint4*)(hb + par * 1024 + ks * 256);
    const __half2 zero = __float2half2_rn(0.f);
    __half2 aA0 = zero, aA1 = zero, aB0 = zero, aB1 = zero;
    __half2 aC0 = zero, aC1 = zero, aD0 = zero, aD1 = zero;
#pragma unroll
    for (int g = 0; g < 12; ++g) {
      uint4 hv = h4[g];
      aA0 = __hfma2(bch2(wreg[g * 16 + 0]), bch2(hv.x), aA0);
      aA1 = __hfma2(bch2(wreg[g * 16 + 1]), bch2(hv.y), aA1);
      aA0 = __hfma2(bch2(wreg[g * 16 + 2]), bch2(hv.z), aA0);
      aA1 = __hfma2(bch2(wreg[g * 16 + 3]), bch2(hv.w), aA1);
      aB0 = __hfma2(bch2(wreg[g * 16 + 4]), bch2(hv.x), aB0);
      aB1 = __hfma2(bch2(wreg[g * 16 + 5]), bch2(hv.y), aB1);
      aB0 = __hfma2(bch2(wreg[g * 16 + 6]), bch2(hv.z), aB0);
      aB1 = __hfma2(bch2(wreg[g * 16 + 7]), bch2(hv.w), aB1);
      aC0 = __hfma2(bch2(wreg[g * 16 + 8]), bch2(hv.x), aC0);
      aC1 = __hfma2(bch2(wreg[g * 16 + 9]), bch2(hv.y), aC1);
      aC0 = __hfma2(bch2(wreg[g * 16 + 10]), bch2(hv.z), aC0);
      aC1 = __hfma2(bch2(wreg[g * 16 + 11]), bch2(hv.w), aC1);
      aD0 = __hfma2(bch2(wreg[g * 16 + 12]), bch2(hv.x), aD0);
      aD1 = __hfma2(bch2(wreg[g * 16 + 13]), bch2(hv.y), aD1);
      aD0 = __hfma2(bch2(wreg[g * 16 + 14]), bch2(hv.z), aD0);
      aD1 = __hfma2(bch2(wreg[g * 16 + 15]), bch2(hv.w), aD1);
    }
#pragma unroll
    for (int g2 = 0; g2 < 4; ++g2) {
      uint4 hv = h4[12 + g2];
      uint4 wA = Wl4[(0 + g2) * 512 + j];
      uint4 wB = Wl4[(4 + g2) * 512 + j];
      uint4 wC = Wl4[(8 + g2) * 512 + j];
      uint4 wD = Wl4[(12 + g2) * 512 + j];
      aA0 = __hfma2(bch2(wA.x), bch2(hv.x), aA0);
      aA1 = __hfma2(bch2(wA.y), bch2(hv.y), aA1);
      aA0 = __hfma2(bch2(wA.z), bch2(hv.z), aA0);
      aA1 = __hfma2(bch2(wA.w), bch2(hv.w), aA1);
      aB0 = __hfma2(bch2(wB.x), bch2(hv.x), aB0);
      aB1 = __hfma2(bch2(wB.y), bch2(hv.y), aB1);
      aB0 = __hfma2(bch2(wB.z), bch2(hv.z), aB0);
      aB1 = __hfma2(bch2(wB.w), bch2(hv.w), aB1);
      aC0 = __hfma2(bch2(wC.x), bch2(hv.x), aC0);
      aC1 = __hfma2(bch2(wC.y), bch2(hv.y), aC1);
      aC0 = __hfma2(bch2(wC.z), bch2(hv.z), aC0);
      aC1 = __hfma2(bch2(wC.w), bch2(hv.w), aC1);
      aD0 = __hfma2(bch2(wD.x), bch2(hv.x), aD0);
      aD1 = __hfma2(bch2(wD.y), bch2(hv.y), aD1);
      aD0 = __hfma2(bch2(wD.z), bch2(hv.z), aD0);
      aD1 = __hfma2(bch2(wD.w), bch2(hv.w), aD1);
    }
    float s0 = __low2float(aA0) + __high2float(aA0) + __low2float(aA1) + __high2float(aA1);
    float s1 = __low2float(aB0) + __high2float(aB0) + __low2float(aB1) + __high2float(aB1);
    float s2 = __low2float(aC0) + __high2float(aC0) + __low2float(aC1) + __high2float(aC1);
    float s3 = __low2float(aD0) + __high2float(aD0) + __low2float(aD1) + __high2float(aD1);
    s0 = dppadd<0xB1>(s0); s0 = dppadd<0x4E>(s0);
    s1 = dppadd<0xB1>(s1); s1 = dppadd<0x4E>(s1);
    s2 = dppadd<0xB1>(s2); s2 = dppadd<0x4E>(s2);
    s3 = dppadd<0xB1>(s3); s3 = dppadd<0x4E>(s3);
    float f0 = fast_tanh(s0 + u0), f1 = fast_tanh(s1 + u1);
    float f2 = fast_tanh(s2 + u2), f3 = fast_tanh(s3 + u3);
    char* hbn = hb + (par ^ 1) * 1024;
    if (ks == 0) {
      *(__half*)(hbn + c0 * 2) = __float2half(f0);
      *(__half*)(hbn + (128 + c0) * 2) = __float2half(f1);
      *(__half*)(hbn + (256 + c0) * 2) = __float2half(f2);
      *(__half*)(hbn + (384 + c0) * 2) = __float2half(f3);
    }
    if (ks == 1 && t + 1 < T_STEPS) {
      u16* hp = Hseq + (r0 + t + 1) * 512;
      hp[c0] = f2bu(f0); hp[128 + c0] = f2bu(f1);
      hp[256 + c0] = f2bu(f2); hp[384 + c0] = f2bu(f3);
    }
    u0 = un0; u1 = un1; u2 = un2; u3 = un3;
    __syncthreads();
    par ^= 1;
  }
}

// ---------------- launch ----------------
extern "C" void kernel_launch(void* const* d_in, const int* in_sizes, int n_in,
                              void* d_out, int out_size, void* d_ws, size_t ws_size,
                              hipStream_t stream) {
  const float* x   = (const float*)d_in[0];
  const float* enc = (const float*)d_in[1];
  const float* Wh0 = (const float*)d_in[2];
  const float* bh0 = (const float*)d_in[3];
  const float* Wo0 = (const float*)d_in[4];
  const float* bo0 = (const float*)d_in[5];
  const float* Wh1 = (const float*)d_in[6];
  const float* bh1 = (const float*)d_in[7];
  const float* Wo1 = (const float*)d_in[8];
  const float* bo1 = (const float*)d_in[9];
  char* ws = (char*)d_ws;
  u16*    Xbf   = (u16*)(ws);
  __half* U     = (__half*)(ws + 16777216);
  u16*    Hs0   = (u16*)(ws + 16777216 + 33554432);
  u16*    Out0  = (u16*)(ws + 16777216 + 33554432 + 16777216);
  u16*    Hs1   = (u16*)(ws + 16777216 + 33554432 + 2 * 16777216);
  char*   wb    = ws + 16777216 + 33554432 + 3 * 16777216;
  u16*    Bct0  = (u16*)(wb);
  u16*    WhoT0 = (u16*)(wb + 1048576);
  u32*    Wpk0  = (u32*)(wb + 1048576 + 524288);
  u16*    Bct1  = (u16*)(wb + 1048576 + 2 * 524288);
  u16*    WhoT1 = (u16*)(wb + 2 * 1048576 + 2 * 524288);
  u32*    Wpk1  = (u32*)(wb + 2 * 1048576 + 3 * 524288);

  (void)hipFuncSetAttribute((const void*)k_scan4,
                            hipFuncAttributeMaxDynamicSharedMemorySize,
                            SCAN4_LDS_BYTES);

  k_cvt_bf16<<<8192, 256, 0, stream>>>(x, Xbf, 8388608 / 4);
  k_prep_w<<<3584, 256, 0, stream>>>(Wh0, Wo0, Bct0, WhoT0, Wpk0);
  k_prep_w<<<3584, 256, 0, stream>>>(Wh1, Wo1, Bct1, WhoT1, Wpk1);
  k_gemm<0><<<1024, 256, 0, stream>>>(Xbf, Bct0, 8, U, nullptr, nullptr, nullptr, bh0, bo0);
  k_scan4<<<64, 512, SCAN4_LDS_BYTES, stream>>>(Wpk0, U, enc, Hs0);
  k_gemm<1><<<512, 256, 0, stream>>>(Hs0, WhoT0, 4, nullptr, Out0, nullptr, U + 512, nullptr, nullptr);
  k_gemm<0><<<1024, 256, 0, stream>>>(Out0, Bct1, 8, U, nullptr, nullptr, nullptr, bh1, bo1);
  k_scan4<<<64, 512, SCAN4_LDS_BYTES, stream>>>(Wpk1, U, nullptr, Hs1);
  k_gemm<2><<<512, 256, 0, stream>>>(Hs1, WhoT1, 4, nullptr, nullptr, (float*)d_out, U + 512, nullptr, nullptr);
}